// Round 1
// baseline (584.748 us; speedup 1.0000x reference)
//
#include <hip/hip_runtime.h>

#define NUM_ATOMS 40000
#define NUM_EDGES 640000
// FAN_IN = NFM = FAN_OUT = 128

// ---------------------------------------------------------------------------
// Kernel R: CSR row offsets from sorted seg_i.
// rs[i] = lower_bound(seg_i, i) for i in [0, NUM_ATOMS]. rs[NUM_ATOMS] = NUM_EDGES.
// ---------------------------------------------------------------------------
__global__ void k_rowstart(const int* __restrict__ seg, int* __restrict__ rs) {
  const int i = blockIdx.x * blockDim.x + threadIdx.x;
  if (i > NUM_ATOMS) return;
  int lo = 0, hi = NUM_EDGES;
  while (lo < hi) {
    const int mid = (lo + hi) >> 1;
    if (seg[mid] < i) lo = mid + 1; else hi = mid;
  }
  rs[i] = lo;
}

// ---------------------------------------------------------------------------
// Kernel A: f[M][128] = x[M][128] @ W_in[128][128]  (fp32 vector GEMM)
// block = 512 threads, tile 128 rows x 128 cols, thread tile 8m x 4n.
// LDS: xT[k][m] (64 KB, transposed, conflict-free: staging lanes vary m) +
//      W[k][n] (64 KB). Reads: xT float4 broadcast, W float2 2-way -> free.
// ---------------------------------------------------------------------------
__global__ __launch_bounds__(512, 2) void k_gemm1(
    const float* __restrict__ x, const float* __restrict__ Win,
    float* __restrict__ f) {
  __shared__ float xT[128 * 128];  // [k][m]
  __shared__ float Wl[128 * 128];  // [k][n]
  const int t = threadIdx.x;
  const int m0 = blockIdx.x * 128;

  // stage W_in (coalesced float4 copy)
  {
    const float4* Wg = (const float4*)Win;
    float4* Ws = (float4*)Wl;
#pragma unroll
    for (int i = 0; i < 8; ++i) Ws[t + i * 512] = Wg[t + i * 512];
  }
  // stage x transposed: lane m = t&127 (consecutive lanes -> consecutive m ->
  // stride-1 LDS writes, conflict-free). Global reads are 16B/lane strided;
  // total x volume is only 20.5 MB so coalescing here is non-critical.
  {
    const int m = t & 127;
    const int kq = t >> 7;  // 0..3
    int mg = m0 + m;
    if (mg >= NUM_ATOMS) mg = NUM_ATOMS - 1;  // clamp (stores are guarded)
    const float4* xg = (const float4*)(x + (size_t)mg * 128);
#pragma unroll
    for (int i = 0; i < 8; ++i) {
      const int k4 = kq + i * 4;  // 0..31
      const float4 v = xg[k4];
      const int k = k4 * 4;
      xT[(k + 0) * 128 + m] = v.x;
      xT[(k + 1) * 128 + m] = v.y;
      xT[(k + 2) * 128 + m] = v.z;
      xT[(k + 3) * 128 + m] = v.w;
    }
  }
  __syncthreads();

  const int tx = t & 31;  // n = 2tx, 2tx+1, 64+2tx, 64+2tx+1
  const int ty = t >> 5;  // 0..15: m = 4ty..4ty+3, 64+4ty..64+4ty+3
  float acc[8][4];
#pragma unroll
  for (int i = 0; i < 8; ++i)
#pragma unroll
    for (int j = 0; j < 4; ++j) acc[i][j] = 0.f;

#pragma unroll 4
  for (int k = 0; k < 128; ++k) {
    const float4 a0 = *(const float4*)&xT[k * 128 + 4 * ty];
    const float4 a1 = *(const float4*)&xT[k * 128 + 64 + 4 * ty];
    const float2 b0 = *(const float2*)&Wl[k * 128 + 2 * tx];
    const float2 b1 = *(const float2*)&Wl[k * 128 + 64 + 2 * tx];
    const float av[8] = {a0.x, a0.y, a0.z, a0.w, a1.x, a1.y, a1.z, a1.w};
    const float bv[4] = {b0.x, b0.y, b1.x, b1.y};
#pragma unroll
    for (int i = 0; i < 8; ++i)
#pragma unroll
      for (int j = 0; j < 4; ++j) acc[i][j] += av[i] * bv[j];
  }

#pragma unroll
  for (int i = 0; i < 8; ++i) {
    const int m = (i < 4) ? (4 * ty + i) : (64 + 4 * ty + (i - 4));
    const int mg = m0 + m;
    if (mg < NUM_ATOMS) {
      float2* o = (float2*)(f + (size_t)mg * 128);
      o[tx]      = make_float2(acc[i][0], acc[i][1]);
      o[32 + tx] = make_float2(acc[i][2], acc[i][3]);
    }
  }
}

// ---------------------------------------------------------------------------
// Kernel B (fused): per atom i, conv[i] = sum_e w_ij[e] * f[idx_j[e]], then
// out[i] = conv[i] @ W_out + b_out.
// block = 256 threads (4 waves), 32 atoms/block: wave w streams edges of its
// 8 atoms (seg-sorted -> w_ij rows sequential; 512B coalesced row loads,
// float2/lane), conv rows -> LDS. Then a block-wide 32x128 @ 128x128 GEMM2
// against W_out staged once in LDS (amortized 32x).
// LDS: W_out 64 KB + conv 16 KB = 80 KB -> exactly 2 blocks/CU (8 waves/CU).
// ---------------------------------------------------------------------------
__global__ __launch_bounds__(256, 2) void k_conv_out(
    const float* __restrict__ f, const float* __restrict__ w_ij,
    const int* __restrict__ idx_j, const int* __restrict__ rs,
    const float* __restrict__ Wout, const float* __restrict__ bout,
    float* __restrict__ out) {
  __shared__ float Wl[128 * 128];   // 64 KB [c][n]
  __shared__ float conv[32 * 128];  // 16 KB [a_local][c]
  const int t = threadIdx.x;

  // stage W_out
  {
    const float4* Wg = (const float4*)Wout;
    float4* Ws = (float4*)Wl;
#pragma unroll
    for (int i = 0; i < 16; ++i) Ws[t + i * 256] = Wg[t + i * 256];
  }

  const int wv = t >> 6;  // wave 0..3
  const int l = t & 63;   // lane: channels 2l, 2l+1
  const int abase = blockIdx.x * 32;

#pragma unroll 1
  for (int ai = 0; ai < 8; ++ai) {
    const int al = wv * 8 + ai;
    const int a = abase + al;
    float accx = 0.f, accy = 0.f;
    const int e0 = rs[a];
    const int e1 = rs[a + 1];
    int e = e0;
    // unroll-4: batch independent idx loads, then w/f row loads, to keep
    // ~4 KB per wave in flight against ~900-cycle HBM latency.
    for (; e + 4 <= e1; e += 4) {
      const int j0 = idx_j[e + 0];
      const int j1 = idx_j[e + 1];
      const int j2 = idx_j[e + 2];
      const int j3 = idx_j[e + 3];
      const float2 w0 = ((const float2*)(w_ij + (size_t)(e + 0) * 128))[l];
      const float2 w1 = ((const float2*)(w_ij + (size_t)(e + 1) * 128))[l];
      const float2 w2 = ((const float2*)(w_ij + (size_t)(e + 2) * 128))[l];
      const float2 w3 = ((const float2*)(w_ij + (size_t)(e + 3) * 128))[l];
      const float2 f0 = ((const float2*)(f + (size_t)j0 * 128))[l];
      const float2 f1 = ((const float2*)(f + (size_t)j1 * 128))[l];
      const float2 f2 = ((const float2*)(f + (size_t)j2 * 128))[l];
      const float2 f3 = ((const float2*)(f + (size_t)j3 * 128))[l];
      accx += w0.x * f0.x; accy += w0.y * f0.y;
      accx += w1.x * f1.x; accy += w1.y * f1.y;
      accx += w2.x * f2.x; accy += w2.y * f2.y;
      accx += w3.x * f3.x; accy += w3.y * f3.y;
    }
    for (; e < e1; ++e) {
      const int j = idx_j[e];
      const float2 w = ((const float2*)(w_ij + (size_t)e * 128))[l];
      const float2 fv = ((const float2*)(f + (size_t)j * 128))[l];
      accx += w.x * fv.x; accy += w.y * fv.y;
    }
    // conv[a_local][c]: consecutive lanes -> consecutive float2 -> conflict-free
    ((float2*)(conv + al * 128))[l] = make_float2(accx, accy);
  }
  __syncthreads();

  // GEMM2: out[32][128] = conv[32][128] @ Wl + bias. Thread tile 4 atoms x 4 n.
  const int tx = t & 31;  // n = 2tx, 2tx+1, 64+2tx, 64+2tx+1
  const int ty = t >> 5;  // 0..7: atoms 4ty..4ty+3
  const float2 bb0 = ((const float2*)bout)[tx];
  const float2 bb1 = ((const float2*)bout)[32 + tx];
  float acc2[4][4];
#pragma unroll
  for (int i = 0; i < 4; ++i) {
    acc2[i][0] = bb0.x; acc2[i][1] = bb0.y;
    acc2[i][2] = bb1.x; acc2[i][3] = bb1.y;
  }
#pragma unroll 4
  for (int c = 0; c < 128; ++c) {
    const float2 b0 = *(const float2*)&Wl[c * 128 + 2 * tx];       // 2-way: free
    const float2 b1 = *(const float2*)&Wl[c * 128 + 64 + 2 * tx];  // 2-way: free
#pragma unroll
    for (int i = 0; i < 4; ++i) {
      const float cv = conv[(4 * ty + i) * 128 + c];  // broadcast: free
      acc2[i][0] += cv * b0.x;
      acc2[i][1] += cv * b0.y;
      acc2[i][2] += cv * b1.x;
      acc2[i][3] += cv * b1.y;
    }
  }
#pragma unroll
  for (int i = 0; i < 4; ++i) {
    const int a = abase + 4 * ty + i;  // 40000 = 1250*32, always in range
    float2* o = (float2*)(out + (size_t)a * 128);
    o[tx]      = make_float2(acc2[i][0], acc2[i][1]);
    o[32 + tx] = make_float2(acc2[i][2], acc2[i][3]);
  }
}

// ---------------------------------------------------------------------------
extern "C" void kernel_launch(void* const* d_in, const int* in_sizes, int n_in,
                              void* d_out, int out_size, void* d_ws, size_t ws_size,
                              hipStream_t stream) {
  const float* x    = (const float*)d_in[0];
  const float* w_ij = (const float*)d_in[1];
  const int*   seg  = (const int*)d_in[2];
  const int*   idxj = (const int*)d_in[3];
  // d_in[4] = seg_i_sum scalar (== NUM_ATOMS, hardcoded)
  const float* Win  = (const float*)d_in[5];
  const float* Wout = (const float*)d_in[6];
  const float* bout = (const float*)d_in[7];
  float* out = (float*)d_out;

  // workspace layout: f (40000*128 f32 = 20.48 MB) | row_start (40001 i32)
  float* f = (float*)d_ws;
  int* rs = (int*)((char*)d_ws + (size_t)NUM_ATOMS * 128 * sizeof(float));

  k_rowstart<<<(NUM_ATOMS + 1 + 255) / 256, 256, 0, stream>>>(seg, rs);
  k_gemm1<<<(NUM_ATOMS + 127) / 128, 512, 0, stream>>>(x, Win, f);
  k_conv_out<<<NUM_ATOMS / 32, 256, 0, stream>>>(f, w_ij, idxj, rs, Wout, bout, out);
}

// Round 2
// 547.549 us; speedup vs baseline: 1.0679x; 1.0679x over previous
//
#include <hip/hip_runtime.h>

#define NUM_ATOMS 40000
#define NUM_EDGES 640000
// FAN_IN = NFM = FAN_OUT = 128

// ---------------------------------------------------------------------------
// Kernel R: CSR row offsets from sorted seg_i.
// rs[i] = lower_bound(seg_i, i) for i in [0, NUM_ATOMS]. rs[NUM_ATOMS] = NUM_EDGES.
// ---------------------------------------------------------------------------
__global__ void k_rowstart(const int* __restrict__ seg, int* __restrict__ rs) {
  const int i = blockIdx.x * blockDim.x + threadIdx.x;
  if (i > NUM_ATOMS) return;
  int lo = 0, hi = NUM_EDGES;
  while (lo < hi) {
    const int mid = (lo + hi) >> 1;
    if (seg[mid] < i) lo = mid + 1; else hi = mid;
  }
  rs[i] = lo;
}

// ---------------------------------------------------------------------------
// Kernel G: out[M][128] = A[M][128] @ W[128][128] (+ bias)   fp32 vector GEMM
// block = 512 threads, tile 128 rows x 128 cols, thread tile 8m x 4n.
// LDS: AT[k][m] (64 KB, transposed; staging lanes vary m -> stride-1 writes) +
//      W[k][n] (64 KB). Reads: AT float4 broadcast, W float2 2-way -> free.
// 128 KB LDS -> 1 block/CU; 313 blocks; ~13-25 us, BW-trivial.
// ---------------------------------------------------------------------------
__global__ __launch_bounds__(512, 2) void k_gemm128(
    const float* __restrict__ A, const float* __restrict__ W,
    const float* __restrict__ bias, float* __restrict__ out) {
  __shared__ float AT[128 * 128];  // [k][m]
  __shared__ float Wl[128 * 128];  // [k][n]
  const int t = threadIdx.x;
  const int m0 = blockIdx.x * 128;

  // stage W (coalesced float4 copy)
  {
    const float4* Wg = (const float4*)W;
    float4* Ws = (float4*)Wl;
#pragma unroll
    for (int i = 0; i < 8; ++i) Ws[t + i * 512] = Wg[t + i * 512];
  }
  // stage A transposed: lane m = t&127 -> stride-1 LDS writes, conflict-free.
  {
    const int m = t & 127;
    const int kq = t >> 7;  // 0..3
    int mg = m0 + m;
    if (mg >= NUM_ATOMS) mg = NUM_ATOMS - 1;  // clamp (stores are guarded)
    const float4* ag = (const float4*)(A + (size_t)mg * 128);
#pragma unroll
    for (int i = 0; i < 8; ++i) {
      const int k4 = kq + i * 4;  // 0..31
      const float4 v = ag[k4];
      const int k = k4 * 4;
      AT[(k + 0) * 128 + m] = v.x;
      AT[(k + 1) * 128 + m] = v.y;
      AT[(k + 2) * 128 + m] = v.z;
      AT[(k + 3) * 128 + m] = v.w;
    }
  }
  __syncthreads();

  const int tx = t & 31;  // n = 2tx, 2tx+1, 64+2tx, 64+2tx+1
  const int ty = t >> 5;  // 0..15: m = 4ty..4ty+3, 64+4ty..64+4ty+3

  float binit[4] = {0.f, 0.f, 0.f, 0.f};
  if (bias != nullptr) {
    const float2 bb0 = ((const float2*)bias)[tx];
    const float2 bb1 = ((const float2*)bias)[32 + tx];
    binit[0] = bb0.x; binit[1] = bb0.y; binit[2] = bb1.x; binit[3] = bb1.y;
  }
  float acc[8][4];
#pragma unroll
  for (int i = 0; i < 8; ++i)
#pragma unroll
    for (int j = 0; j < 4; ++j) acc[i][j] = binit[j];

#pragma unroll 4
  for (int k = 0; k < 128; ++k) {
    const float4 a0 = *(const float4*)&AT[k * 128 + 4 * ty];
    const float4 a1 = *(const float4*)&AT[k * 128 + 64 + 4 * ty];
    const float2 b0 = *(const float2*)&Wl[k * 128 + 2 * tx];
    const float2 b1 = *(const float2*)&Wl[k * 128 + 64 + 2 * tx];
    const float av[8] = {a0.x, a0.y, a0.z, a0.w, a1.x, a1.y, a1.z, a1.w};
    const float bv[4] = {b0.x, b0.y, b1.x, b1.y};
#pragma unroll
    for (int i = 0; i < 8; ++i)
#pragma unroll
      for (int j = 0; j < 4; ++j) acc[i][j] += av[i] * bv[j];
  }

#pragma unroll
  for (int i = 0; i < 8; ++i) {
    const int m = (i < 4) ? (4 * ty + i) : (64 + 4 * ty + (i - 4));
    const int mg = m0 + m;
    if (mg < NUM_ATOMS) {
      float2* o = (float2*)(out + (size_t)mg * 128);
      o[tx]      = make_float2(acc[i][0], acc[i][1]);
      o[32 + tx] = make_float2(acc[i][2], acc[i][3]);
    }
  }
}

// ---------------------------------------------------------------------------
// Kernel C: conv[a] = sum_{e in [rs[a],rs[a+1])} w_ij[e] * f[idx_j[e]]
// ONE WAVE PER ATOM. No LDS, no barriers -> high occupancy, max memory-level
// parallelism. Per chunk of <=64 edges: one coalesced idx load, j broadcast
// via __shfl, then all w-row / f-row loads (512 B each, perfectly coalesced)
// issue with no inter-batch dependences. Lane l owns channels 2l, 2l+1.
// ---------------------------------------------------------------------------
__global__ __launch_bounds__(256) void k_conv(
    const float* __restrict__ f, const float* __restrict__ w_ij,
    const int* __restrict__ idx_j, const int* __restrict__ rs,
    float* __restrict__ conv) {
  const int wv = threadIdx.x >> 6;
  const int l = threadIdx.x & 63;
  const int a = blockIdx.x * 4 + wv;  // 40000 = 10000 * 4, always in range

  const int e0 = rs[a];
  const int e1 = rs[a + 1];
  float accx = 0.f, accy = 0.f;

  for (int base = e0; base < e1; base += 64) {
    const int n = min(64, e1 - base);
    int j = 0;
    if (l < n) j = idx_j[base + l];
    int k = 0;
    for (; k + 4 <= n; k += 4) {
      const int j0 = __shfl(j, k + 0);
      const int j1 = __shfl(j, k + 1);
      const int j2 = __shfl(j, k + 2);
      const int j3 = __shfl(j, k + 3);
      const float2 w0 = ((const float2*)(w_ij + (size_t)(base + k + 0) * 128))[l];
      const float2 w1 = ((const float2*)(w_ij + (size_t)(base + k + 1) * 128))[l];
      const float2 w2 = ((const float2*)(w_ij + (size_t)(base + k + 2) * 128))[l];
      const float2 w3 = ((const float2*)(w_ij + (size_t)(base + k + 3) * 128))[l];
      const float2 f0 = ((const float2*)(f + (size_t)j0 * 128))[l];
      const float2 f1 = ((const float2*)(f + (size_t)j1 * 128))[l];
      const float2 f2 = ((const float2*)(f + (size_t)j2 * 128))[l];
      const float2 f3 = ((const float2*)(f + (size_t)j3 * 128))[l];
      accx += w0.x * f0.x; accy += w0.y * f0.y;
      accx += w1.x * f1.x; accy += w1.y * f1.y;
      accx += w2.x * f2.x; accy += w2.y * f2.y;
      accx += w3.x * f3.x; accy += w3.y * f3.y;
    }
    for (; k < n; ++k) {
      const int jk = __shfl(j, k);
      const float2 w = ((const float2*)(w_ij + (size_t)(base + k) * 128))[l];
      const float2 fv = ((const float2*)(f + (size_t)jk * 128))[l];
      accx += w.x * fv.x; accy += w.y * fv.y;
    }
  }
  // coalesced float2 store; zero-edge atoms correctly write 0
  ((float2*)(conv + (size_t)a * 128))[l] = make_float2(accx, accy);
}

// ---------------------------------------------------------------------------
extern "C" void kernel_launch(void* const* d_in, const int* in_sizes, int n_in,
                              void* d_out, int out_size, void* d_ws, size_t ws_size,
                              hipStream_t stream) {
  const float* x    = (const float*)d_in[0];
  const float* w_ij = (const float*)d_in[1];
  const int*   seg  = (const int*)d_in[2];
  const int*   idxj = (const int*)d_in[3];
  // d_in[4] = seg_i_sum scalar (== NUM_ATOMS, hardcoded)
  const float* Win  = (const float*)d_in[5];
  const float* Wout = (const float*)d_in[6];
  const float* bout = (const float*)d_in[7];
  float* out = (float*)d_out;

  // workspace: f (20.48 MB) | conv (20.48 MB) | rs (40001 i32)
  float* f    = (float*)d_ws;
  float* conv = (float*)((char*)d_ws + (size_t)NUM_ATOMS * 128 * sizeof(float));
  int*   rs   = (int*)((char*)d_ws + 2 * (size_t)NUM_ATOMS * 128 * sizeof(float));

  k_rowstart<<<(NUM_ATOMS + 1 + 255) / 256, 256, 0, stream>>>(seg, rs);
  k_gemm128<<<(NUM_ATOMS + 127) / 128, 512, 0, stream>>>(x, Win, nullptr, f);
  k_conv<<<NUM_ATOMS / 4, 256, 0, stream>>>(f, w_ij, idxj, rs, conv);
  k_gemm128<<<(NUM_ATOMS + 127) / 128, 512, 0, stream>>>(conv, Wout, bout, out);
}

// Round 3
// 546.643 us; speedup vs baseline: 1.0697x; 1.0017x over previous
//
#include <hip/hip_runtime.h>

#define NUM_ATOMS 40000
#define NUM_EDGES 640000
// FAN_IN = NFM = FAN_OUT = 128

// ---------------------------------------------------------------------------
// Kernel R: CSR row offsets from sorted seg_i.
// rs[i] = lower_bound(seg_i, i) for i in [0, NUM_ATOMS]. rs[NUM_ATOMS] = NUM_EDGES.
// ---------------------------------------------------------------------------
__global__ void k_rowstart(const int* __restrict__ seg, int* __restrict__ rs) {
  const int i = blockIdx.x * blockDim.x + threadIdx.x;
  if (i > NUM_ATOMS) return;
  int lo = 0, hi = NUM_EDGES;
  while (lo < hi) {
    const int mid = (lo + hi) >> 1;
    if (seg[mid] < i) lo = mid + 1; else hi = mid;
  }
  rs[i] = lo;
}

// ---------------------------------------------------------------------------
// Kernel G: out[M][128] = A[M][128] @ W[128][128] (+ bias)   fp32 vector GEMM
// (unchanged from R2 — ~15-20 us each; conv is this round's single variable)
// ---------------------------------------------------------------------------
__global__ __launch_bounds__(512, 2) void k_gemm128(
    const float* __restrict__ A, const float* __restrict__ W,
    const float* __restrict__ bias, float* __restrict__ out) {
  __shared__ float AT[128 * 128];  // [k][m]
  __shared__ float Wl[128 * 128];  // [k][n]
  const int t = threadIdx.x;
  const int m0 = blockIdx.x * 128;

  {
    const float4* Wg = (const float4*)W;
    float4* Ws = (float4*)Wl;
#pragma unroll
    for (int i = 0; i < 8; ++i) Ws[t + i * 512] = Wg[t + i * 512];
  }
  {
    const int m = t & 127;
    const int kq = t >> 7;  // 0..3
    int mg = m0 + m;
    if (mg >= NUM_ATOMS) mg = NUM_ATOMS - 1;  // clamp (stores are guarded)
    const float4* ag = (const float4*)(A + (size_t)mg * 128);
#pragma unroll
    for (int i = 0; i < 8; ++i) {
      const int k4 = kq + i * 4;  // 0..31
      const float4 v = ag[k4];
      const int k = k4 * 4;
      AT[(k + 0) * 128 + m] = v.x;
      AT[(k + 1) * 128 + m] = v.y;
      AT[(k + 2) * 128 + m] = v.z;
      AT[(k + 3) * 128 + m] = v.w;
    }
  }
  __syncthreads();

  const int tx = t & 31;
  const int ty = t >> 5;

  float binit[4] = {0.f, 0.f, 0.f, 0.f};
  if (bias != nullptr) {
    const float2 bb0 = ((const float2*)bias)[tx];
    const float2 bb1 = ((const float2*)bias)[32 + tx];
    binit[0] = bb0.x; binit[1] = bb0.y; binit[2] = bb1.x; binit[3] = bb1.y;
  }
  float acc[8][4];
#pragma unroll
  for (int i = 0; i < 8; ++i)
#pragma unroll
    for (int j = 0; j < 4; ++j) acc[i][j] = binit[j];

#pragma unroll 4
  for (int k = 0; k < 128; ++k) {
    const float4 a0 = *(const float4*)&AT[k * 128 + 4 * ty];
    const float4 a1 = *(const float4*)&AT[k * 128 + 64 + 4 * ty];
    const float2 b0 = *(const float2*)&Wl[k * 128 + 2 * tx];
    const float2 b1 = *(const float2*)&Wl[k * 128 + 64 + 2 * tx];
    const float av[8] = {a0.x, a0.y, a0.z, a0.w, a1.x, a1.y, a1.z, a1.w};
    const float bv[4] = {b0.x, b0.y, b1.x, b1.y};
#pragma unroll
    for (int i = 0; i < 8; ++i)
#pragma unroll
      for (int j = 0; j < 4; ++j) acc[i][j] += av[i] * bv[j];
  }

#pragma unroll
  for (int i = 0; i < 8; ++i) {
    const int m = (i < 4) ? (4 * ty + i) : (64 + 4 * ty + (i - 4));
    const int mg = m0 + m;
    if (mg < NUM_ATOMS) {
      float2* o = (float2*)(out + (size_t)mg * 128);
      o[tx]      = make_float2(acc[i][0], acc[i][1]);
      o[32 + tx] = make_float2(acc[i][2], acc[i][3]);
    }
  }
}

// ---------------------------------------------------------------------------
// Kernel C: conv[a] = sum_{e in [rs[a],rs[a+1])} w_ij[e] * f[idx_j[e]]
// One wave per atom. Per <=32-edge chunk: preload ALL w-rows and f-rows into
// register arrays (up to 64 independent 512B loads = 16 KB in flight per
// wave, no intervening waits), then one wait + FMA burst. Guards at
// granularity 8 with clamped index: over-issued rows are duplicates of the
// last valid row (L1 hits, not HBM) and are excluded from the FMA phase.
// Lane l owns channels 2l, 2l+1. ~128 data VGPRs -> ~3 waves/SIMD; in-flight
// bytes/CU ~190 KB >> ~25 KB latency-BW product -> HBM-bound.
// ---------------------------------------------------------------------------
__global__ __launch_bounds__(256) void k_conv(
    const float* __restrict__ f, const float* __restrict__ w_ij,
    const int* __restrict__ idx_j, const int* __restrict__ rs,
    float* __restrict__ conv) {
  const int wv = threadIdx.x >> 6;
  const int l = threadIdx.x & 63;
  const int a = blockIdx.x * 4 + wv;  // 40000 = 10000 * 4, always in range

  const int e0 = rs[a];
  const int e1 = rs[a + 1];
  float accx = 0.f, accy = 0.f;

  for (int base = e0; base < e1; base += 32) {
    const int n = min(32, e1 - base);  // wave-uniform
    const int nm1 = n - 1;
    // one coalesced idx load for the chunk (lanes >= n masked off)
    int j = 0;
    if (l < n) j = idx_j[base + l];

    float2 wr[32], fr[32];
    // ---- preload w rows (independent of idx) ----
#pragma unroll
    for (int g = 0; g < 4; ++g) {
      if (n > g * 8) {
#pragma unroll
        for (int k = g * 8; k < g * 8 + 8; ++k) {
          const int kk = min(k, nm1);
          wr[k] = ((const float2*)(w_ij + (size_t)(base + kk) * 128))[l];
        }
      }
    }
    // ---- preload f rows (depend only on the single idx load) ----
#pragma unroll
    for (int g = 0; g < 4; ++g) {
      if (n > g * 8) {
#pragma unroll
        for (int k = g * 8; k < g * 8 + 8; ++k) {
          const int kk = min(k, nm1);
          const int jk = __shfl(j, kk);
          fr[k] = ((const float2*)(f + (size_t)jk * 128))[l];
        }
      }
    }
    // ---- FMA burst ----
#pragma unroll
    for (int g = 0; g < 4; ++g) {
      if (n > g * 8) {
#pragma unroll
        for (int k = g * 8; k < g * 8 + 8; ++k) {
          if (k < n) {
            accx += wr[k].x * fr[k].x;
            accy += wr[k].y * fr[k].y;
          }
        }
      }
    }
  }
  // coalesced float2 store; zero-edge atoms correctly write 0
  ((float2*)(conv + (size_t)a * 128))[l] = make_float2(accx, accy);
}

// ---------------------------------------------------------------------------
extern "C" void kernel_launch(void* const* d_in, const int* in_sizes, int n_in,
                              void* d_out, int out_size, void* d_ws, size_t ws_size,
                              hipStream_t stream) {
  const float* x    = (const float*)d_in[0];
  const float* w_ij = (const float*)d_in[1];
  const int*   seg  = (const int*)d_in[2];
  const int*   idxj = (const int*)d_in[3];
  // d_in[4] = seg_i_sum scalar (== NUM_ATOMS, hardcoded)
  const float* Win  = (const float*)d_in[5];
  const float* Wout = (const float*)d_in[6];
  const float* bout = (const float*)d_in[7];
  float* out = (float*)d_out;

  // workspace: f (20.48 MB) | conv (20.48 MB) | rs (40001 i32)
  float* f    = (float*)d_ws;
  float* conv = (float*)((char*)d_ws + (size_t)NUM_ATOMS * 128 * sizeof(float));
  int*   rs   = (int*)((char*)d_ws + 2 * (size_t)NUM_ATOMS * 128 * sizeof(float));

  k_rowstart<<<(NUM_ATOMS + 1 + 255) / 256, 256, 0, stream>>>(seg, rs);
  k_gemm128<<<(NUM_ATOMS + 127) / 128, 512, 0, stream>>>(x, Win, nullptr, f);
  k_conv<<<NUM_ATOMS / 4, 256, 0, stream>>>(f, w_ij, idxj, rs, conv);
  k_gemm128<<<(NUM_ATOMS + 127) / 128, 512, 0, stream>>>(conv, Wout, bout, out);
}